// Round 1
// baseline (788.399 us; speedup 1.0000x reference)
//
#include <hip/hip_runtime.h>

// Problem constants (from reference):
//   BATCH = 1048576, EMB_DIM = 146, N_GENRES = 18, emb width = 128
// Output row = 146 f32 = 584 B = 73 * float2  -> every row 8B-aligned.
//   float2 0..63  : embedding row (128 f32 = 64 float2, table row 512 B aligned)
//   float2 64..72 : genre row (18 f32 = 9 float2, table row 72 B -> 8B aligned)

#define ROW_F2   73u
#define EMB_F2   64u
#define GENRE_F2 9u
#define TOTAL_F2 (1048576u * ROW_F2)   // 76,546,048 < 2^31

__global__ __launch_bounds__(256) void item_emb_gather_concat(
    const int* __restrict__ idx,        // [BATCH]
    const float2* __restrict__ emb,     // [NUM_ITEMS][64] as float2
    const float2* __restrict__ genre,   // [NUM_ITEMS][9]  as float2
    float2* __restrict__ out)           // [BATCH][73] as float2
{
    unsigned g = blockIdx.x * blockDim.x + threadIdx.x;
    if (g >= TOTAL_F2) return;

    unsigned row = g / ROW_F2;                 // 32-bit magic-mul division
    unsigned c2  = g - row * ROW_F2;

    int item = idx[row];                       // 73 lanes broadcast same addr

    float2 v;
    if (c2 < EMB_F2) {
        v = emb[(unsigned long long)item * EMB_F2 + c2];
    } else {
        v = genre[(unsigned long long)item * GENRE_F2 + (c2 - EMB_F2)];
    }
    out[g] = v;
}

extern "C" void kernel_launch(void* const* d_in, const int* in_sizes, int n_in,
                              void* d_out, int out_size, void* d_ws, size_t ws_size,
                              hipStream_t stream) {
    const int*    idx   = (const int*)d_in[0];
    const float2* emb   = (const float2*)d_in[1];
    const float2* genre = (const float2*)d_in[2];
    float2*       out   = (float2*)d_out;

    const unsigned block = 256;
    const unsigned grid  = (TOTAL_F2 + block - 1) / block;  // 299,008 blocks
    item_emb_gather_concat<<<grid, block, 0, stream>>>(idx, emb, genre, out);
}